// Round 2
// baseline (415.472 us; speedup 1.0000x reference)
//
#include <hip/hip_runtime.h>
#include <hip/hip_bf16.h>

#define D   128   // EMBED_DIM
#define D2  256   // 2*EMBED_DIM

typedef short bf16x8 __attribute__((ext_vector_type(8)));
typedef float f32x4  __attribute__((ext_vector_type(4)));

__device__ __forceinline__ float bf2f(unsigned short u) {
    return __uint_as_float(((unsigned int)u) << 16);
}
__device__ __forceinline__ float bflo(unsigned int p) { return __uint_as_float(p << 16); }
__device__ __forceinline__ float bfhi(unsigned int p) { return __uint_as_float(p & 0xffff0000u); }
__device__ __forceinline__ unsigned short f2bf(float f) {
    __hip_bfloat16 h = __float2bfloat16(f);
    return *(unsigned short*)&h;
}

template<bool BF>
__device__ __forceinline__ float ld1(const void* p, size_t i) {
    if constexpr (BF) return bf2f(((const unsigned short*)p)[i]);
    else              return ((const float*)p)[i];
}

// ---------------------------------------------------------------------------
// Kernel 0: runtime layout detection (1 thread).
// flags[0] = 1 if float tensors are bf16-packed, 0 if fp32.
//   Discriminator: low 16 bits of each 32-bit word of emb_u. bf16-packed ->
//   low half is a bf16 value ~0.1 scale, exponent bits[14:7] in [90,130)
//   (~100% of words). fp32 -> low half is uniform mantissa bits (~16% hit).
// flags[1] = mask element width: 0 = 4-byte, 1 = 1-byte, 2 = 2-byte.
//   mask[0][0] and mask[0][1] are guaranteed true (lengths >= 10).
//   int32/fp32 true -> byte1 == 0;  int8 true -> bytes {1,1};
//   bf16 1.0 -> bytes {0x80, 0x3F}.
// ---------------------------------------------------------------------------
__global__ void detect_kernel(const unsigned int* __restrict__ probe,
                              const unsigned char* __restrict__ mask,
                              int* __restrict__ flags)
{
    if (threadIdx.x == 0 && blockIdx.x == 0) {
        int cnt = 0;
        for (int i = 0; i < 256; ++i) {
            unsigned int e = (probe[i] >> 7) & 0xffu;
            if (e >= 90 && e < 130) ++cnt;
        }
        flags[0] = (cnt >= 128) ? 1 : 0;
        int mm;
        if (mask[1] == 0)      mm = 0;   // 4-byte (int32 or fp32; nonzero-bits test valid for both)
        else if (mask[0] == 1) mm = 1;   // 1-byte bool
        else                   mm = 2;   // 2-byte (bf16 1.0/0.0)
        flags[1] = mm;
    }
}

// ---------------------------------------------------------------------------
// Kernel 1: attention + concat.  One block (128 threads) per row.
// ---------------------------------------------------------------------------
template<bool BF>
__device__ __forceinline__ void attn_body(
    const int* __restrict__ x_u, const int* __restrict__ x_b,
    const int* __restrict__ items, const void* __restrict__ mask, int mmode,
    const void* __restrict__ emb_u, const void* __restrict__ emb_i,
    const void* __restrict__ emb_b, const void* __restrict__ A,
    unsigned short* __restrict__ h_out, int L)
{
    const int b = blockIdx.x;
    const int t = threadIdx.x;

    __shared__ float hu_s[D];
    __shared__ float sc_s[128];
    __shared__ float w_s[128];
    __shared__ int   it_s[128];

    const int xu = x_u[b];
    const int xb = x_b[b];

    const float hu = ld1<BF>(emb_u, (size_t)xu * D + t);
    hu_s[t] = hu;
    w_s[t]  = 0.f;

    bool valid = false;
    if (t < L) {
        const size_t mi = (size_t)b * L + t;
        it_s[t] = items[mi];
        if (mmode == 0)      valid = ((const int*)mask)[mi] != 0;
        else if (mmode == 1) valid = ((const unsigned char*)mask)[mi] != 0;
        else                 valid = ((const unsigned short*)mask)[mi] != 0;
    }
    __syncthreads();

    // ---- scores[t] = dot(h_u, A[item_t]) ----
    if (t < L) {
        float s = -INFINITY;
        if (valid) {
            float acc = 0.f;
            if constexpr (BF) {
                const uint4*  arow = (const uint4*)((const unsigned short*)A + (size_t)it_s[t] * D);
                const float4* hu4  = (const float4*)hu_s;
                #pragma unroll
                for (int c = 0; c < D / 8; ++c) {
                    uint4  p  = arow[c];
                    float4 ha = hu4[2 * c];
                    float4 hb = hu4[2 * c + 1];
                    acc += ha.x * bflo(p.x) + ha.y * bfhi(p.x)
                         + ha.z * bflo(p.y) + ha.w * bfhi(p.y)
                         + hb.x * bflo(p.z) + hb.y * bfhi(p.z)
                         + hb.z * bflo(p.w) + hb.w * bfhi(p.w);
                }
            } else {
                const float4* arow = (const float4*)((const float*)A + (size_t)it_s[t] * D);
                const float4* hu4  = (const float4*)hu_s;
                #pragma unroll
                for (int c = 0; c < D / 4; ++c) {
                    float4 p = arow[c];
                    float4 h = hu4[c];
                    acc += h.x * p.x + h.y * p.y + h.z * p.z + h.w * p.w;
                }
            }
            s = acc;
        }
        sc_s[t] = s;
    }
    __syncthreads();

    // ---- softmax (unnormalized; divide at the end) ----
    float m = -INFINITY;
    for (int k = 0; k < L; ++k) m = fmaxf(m, sc_s[k]);   // LDS broadcast reads
    if (t < L) w_s[t] = valid ? __expf(sc_s[t] - m) : 0.f;
    __syncthreads();
    float sum = 0.f;
    for (int k = 0; k < L; ++k) sum += w_s[k];
    const float inv = (sum > 0.f) ? 1.f / sum : 0.f;     // NaN guard

    // ---- h_x[t] = (sum_l w_l * emb_i[item_l][t]) * inv ----
    float acc = 0.f;
    for (int l = 0; l < L; ++l) {
        const float w = w_s[l];            // uniform across block
        if (w != 0.f)
            acc += w * ld1<BF>(emb_i, (size_t)it_s[l] * D + t);
    }
    acc *= inv;

    const float hb = ld1<BF>(emb_b, (size_t)xb * D + t);
    h_out[(size_t)b * D2 + t]     = f2bf(hu);
    h_out[(size_t)b * D2 + D + t] = f2bf(hb + acc);
}

__global__ __launch_bounds__(128) void attn_kernel(
    const int* x_u, const int* x_b, const int* items, const void* mask,
    const void* emb_u, const void* emb_i, const void* emb_b, const void* A,
    unsigned short* h_out, int L, const int* __restrict__ flags)
{
    if (flags[0]) attn_body<true >(x_u, x_b, items, mask, flags[1], emb_u, emb_i, emb_b, A, h_out, L);
    else          attn_body<false>(x_u, x_b, items, mask, flags[1], emb_u, emb_i, emb_b, A, h_out, L);
}

// ---------------------------------------------------------------------------
// Kernel 2/3: Y = leaky_relu(X @ W^T + bias).  X [B,256] bf16 (ws), W [256,256]
// in detected dtype.  MFMA 16x16x32_bf16, fragments straight from global.
// ---------------------------------------------------------------------------
template<bool BF>
__device__ __forceinline__ bf16x8 load_w8(const void* W, size_t off) {
    if constexpr (BF) {
        return *(const bf16x8*)((const unsigned short*)W + off);
    } else {
        const float* p = (const float*)W + off;
        float4 a = *(const float4*)p;
        float4 b = *(const float4*)(p + 4);
        bf16x8 r;
        r[0] = (short)f2bf(a.x); r[1] = (short)f2bf(a.y);
        r[2] = (short)f2bf(a.z); r[3] = (short)f2bf(a.w);
        r[4] = (short)f2bf(b.x); r[5] = (short)f2bf(b.y);
        r[6] = (short)f2bf(b.z); r[7] = (short)f2bf(b.w);
        return r;
    }
}

template<bool BF>
__device__ __forceinline__ void fc_body(
    const unsigned short* __restrict__ X, const void* __restrict__ W,
    const void* __restrict__ bias, unsigned short* __restrict__ Y)
{
    const int tid  = threadIdx.x;
    const int wave = tid >> 6;
    const int lane = tid & 63;
    const int l16  = lane & 15;
    const int quad = lane >> 4;
    const int mt   = blockIdx.x * 16;

    bf16x8 afrag[8];
    const size_t abase = (size_t)(mt + l16) * D2 + quad * 8;
    #pragma unroll
    for (int kc = 0; kc < 8; ++kc)
        afrag[kc] = *(const bf16x8*)(X + abase + kc * 32);

    #pragma unroll
    for (int jj = 0; jj < 4; ++jj) {
        const int jt = wave * 4 + jj;
        const size_t bbase = (size_t)(jt * 16 + l16) * D2 + quad * 8;
        f32x4 acc = {0.f, 0.f, 0.f, 0.f};
        #pragma unroll
        for (int kc = 0; kc < 8; ++kc) {
            bf16x8 bfrag = load_w8<BF>(W, bbase + kc * 32);
            acc = __builtin_amdgcn_mfma_f32_16x16x32_bf16(afrag[kc], bfrag, acc, 0, 0, 0);
        }
        const int j  = jt * 16 + l16;
        const float bj = ld1<BF>(bias, j);
        #pragma unroll
        for (int r = 0; r < 4; ++r) {
            float v = acc[r] + bj;
            v = v > 0.f ? v : 0.01f * v;   // leaky_relu
            Y[(size_t)(mt + quad * 4 + r) * D2 + j] = f2bf(v);
        }
    }
}

__global__ __launch_bounds__(256) void fc_mfma_kernel(
    const unsigned short* X, const void* W, const void* bias,
    unsigned short* Y, const int* __restrict__ flags)
{
    if (flags[0]) fc_body<true >(X, W, bias, Y);
    else          fc_body<false>(X, W, bias, Y);
}

// ---------------------------------------------------------------------------
// Kernel 4: out[row] = dot(h2[row], out_w) + out_b.  One wave per row.
// ---------------------------------------------------------------------------
template<bool BF>
__device__ __forceinline__ void out_body(
    const unsigned short* __restrict__ X, const void* __restrict__ out_w,
    const void* __restrict__ out_b, void* __restrict__ out, int B)
{
    const int gid  = blockIdx.x * blockDim.x + threadIdx.x;
    const int row  = gid >> 6;
    const int lane = threadIdx.x & 63;
    if (row >= B) return;

    const uint2 xv = ((const uint2*)(X + (size_t)row * D2))[lane];  // 4 bf16
    const float x0 = bflo(xv.x), x1 = bfhi(xv.x), x2 = bflo(xv.y), x3 = bfhi(xv.y);
    float w0, w1, w2, w3;
    if constexpr (BF) {
        uint2 wv = ((const uint2*)out_w)[lane];
        w0 = bflo(wv.x); w1 = bfhi(wv.x); w2 = bflo(wv.y); w3 = bfhi(wv.y);
    } else {
        float4 wv = ((const float4*)out_w)[lane];
        w0 = wv.x; w1 = wv.y; w2 = wv.z; w3 = wv.w;
    }
    float acc = x0 * w0 + x1 * w1 + x2 * w2 + x3 * w3;
    #pragma unroll
    for (int off = 32; off; off >>= 1) acc += __shfl_down(acc, off);
    if (lane == 0) {
        const float v = acc + ld1<BF>(out_b, 0);
        if constexpr (BF) ((unsigned short*)out)[row] = f2bf(v);
        else              ((float*)out)[row] = v;
    }
}

__global__ __launch_bounds__(256) void out_kernel(
    const unsigned short* X, const void* out_w, const void* out_b,
    void* out, int B, const int* __restrict__ flags)
{
    if (flags[0]) out_body<true >(X, out_w, out_b, out, B);
    else          out_body<false>(X, out_w, out_b, out, B);
}

extern "C" void kernel_launch(void* const* d_in, const int* in_sizes, int n_in,
                              void* d_out, int out_size, void* d_ws, size_t ws_size,
                              hipStream_t stream) {
    const int*  x_u   = (const int*)d_in[0];
    const int*  x_b   = (const int*)d_in[1];
    const int*  items = (const int*)d_in[2];
    const void* mask  = d_in[3];
    const void* emb_u = d_in[4];
    const void* emb_i = d_in[5];
    const void* emb_b = d_in[6];
    const void* A     = d_in[7];
    const void* fc1_w = d_in[8];
    const void* fc1_b = d_in[9];
    const void* fc2_w = d_in[10];
    const void* fc2_b = d_in[11];
    const void* out_w = d_in[12];
    const void* out_b = d_in[13];

    const int B = in_sizes[0];
    const int L = in_sizes[2] / B;

    // ws layout: h [B,256] bf16 (4MB) | h1 [B,256] bf16 (4MB) | flags (64B)
    unsigned short* h  = (unsigned short*)d_ws;
    unsigned short* h1 = h + (size_t)B * D2;
    int* flags = (int*)(h1 + (size_t)B * D2);

    detect_kernel<<<1, 64, 0, stream>>>((const unsigned int*)emb_u,
                                        (const unsigned char*)mask, flags);
    attn_kernel<<<B, 128, 0, stream>>>(x_u, x_b, items, mask,
                                       emb_u, emb_i, emb_b, A, h, L, flags);
    fc_mfma_kernel<<<B / 16, 256, 0, stream>>>(h,  fc1_w, fc1_b, h1, flags);
    fc_mfma_kernel<<<B / 16, 256, 0, stream>>>(h1, fc2_w, fc2_b, h,  flags);
    out_kernel<<<B / 4, 256, 0, stream>>>(h, out_w, out_b, d_out, B, flags);
}

// Round 3
// 329.354 us; speedup vs baseline: 1.2615x; 1.2615x over previous
//
#include <hip/hip_runtime.h>
#include <hip/hip_bf16.h>

#define D   128   // EMBED_DIM
#define D2  256   // 2*EMBED_DIM

typedef short bf16x8 __attribute__((ext_vector_type(8)));
typedef float f32x4  __attribute__((ext_vector_type(4)));

__device__ __forceinline__ float bf2f(unsigned short u) {
    return __uint_as_float(((unsigned int)u) << 16);
}
__device__ __forceinline__ float bflo(unsigned int p) { return __uint_as_float(p << 16); }
__device__ __forceinline__ float bfhi(unsigned int p) { return __uint_as_float(p & 0xffff0000u); }
__device__ __forceinline__ unsigned short f2bf(float f) {
    __hip_bfloat16 h = __float2bfloat16(f);
    return *(unsigned short*)&h;
}

template<bool BF>
__device__ __forceinline__ float ld1(const void* p, size_t i) {
    if constexpr (BF) return bf2f(((const unsigned short*)p)[i]);
    else              return ((const float*)p)[i];
}

// 8 consecutive elements starting at elem_off, as floats.
template<bool BF>
__device__ __forceinline__ void load8f(const void* p, size_t elem_off, float* r) {
    if constexpr (BF) {
        uint4 v = *(const uint4*)((const unsigned short*)p + elem_off);
        r[0]=bflo(v.x); r[1]=bfhi(v.x); r[2]=bflo(v.y); r[3]=bfhi(v.y);
        r[4]=bflo(v.z); r[5]=bfhi(v.z); r[6]=bflo(v.w); r[7]=bfhi(v.w);
    } else {
        const float4* q = (const float4*)((const float*)p + elem_off);
        float4 a = q[0], b = q[1];
        r[0]=a.x; r[1]=a.y; r[2]=a.z; r[3]=a.w;
        r[4]=b.x; r[5]=b.y; r[6]=b.z; r[7]=b.w;
    }
}

// ---------------------------------------------------------------------------
// Kernel 0: runtime layout detection (1 wave).
// flags[0]: 1 = float tensors bf16-packed, 0 = fp32 (low-half exponent test).
// flags[1]: mask elem width: 0 = 4-byte, 1 = 1-byte, 2 = 2-byte.
// ---------------------------------------------------------------------------
__global__ void detect_kernel(const unsigned int* __restrict__ probe,
                              const unsigned char* __restrict__ mask,
                              int* __restrict__ flags)
{
    const int t = threadIdx.x;   // 64
    int cnt = 0;
    for (int i = t; i < 256; i += 64) {
        unsigned int e = (probe[i] >> 7) & 0xffu;
        cnt += (e >= 90 && e < 130) ? 1 : 0;
    }
    #pragma unroll
    for (int o = 32; o; o >>= 1) cnt += __shfl_xor(cnt, o);
    if (t == 0) {
        flags[0] = (cnt >= 128) ? 1 : 0;
        flags[1] = (mask[1] == 0) ? 0 : ((mask[0] == 1) ? 1 : 2);
    }
}

// ---------------------------------------------------------------------------
// Kernel 1: attention + concat.  One block (256 threads, 4 waves) per row.
// Mask is a prefix (arange < length) -> valid items are [0, len).
// ---------------------------------------------------------------------------
template<bool BF>
__device__ __forceinline__ void attn_body(
    const int* __restrict__ x_u, const int* __restrict__ x_b,
    const int* __restrict__ items, const void* __restrict__ mask, int mmode,
    const void* __restrict__ emb_u, const void* __restrict__ emb_i,
    const void* __restrict__ emb_b, const void* __restrict__ Aw,
    unsigned short* __restrict__ h_out, int L)
{
    const int b  = blockIdx.x;
    const int t  = threadIdx.x;        // 0..255
    const int wv = t >> 6, ln = t & 63;

    __shared__ float hu_s[D];
    __shared__ float sc_s[128];
    __shared__ float w_s[128];
    __shared__ int   it_s[128];
    __shared__ int   cnt_s[4];
    __shared__ float redm_s[4];
    __shared__ float reds_s[4];
    __shared__ float part_s[16][D];

    const int xu = x_u[b], xb = x_b[b];
    float hu = 0.f;
    if (t < D) { hu = ld1<BF>(emb_u, (size_t)xu * D + t); hu_s[t] = hu; }

    bool valid = false;
    if (t < L && t < 128) {
        const size_t mi = (size_t)b * L + t;
        it_s[t] = items[mi];
        if (mmode == 0)      valid = ((const int*)mask)[mi] != 0;
        else if (mmode == 1) valid = ((const unsigned char*)mask)[mi] != 0;
        else                 valid = ((const unsigned short*)mask)[mi] != 0;
    }
    unsigned long long bm = __ballot(valid);
    if (ln == 0) cnt_s[wv] = __popcll(bm);
    __syncthreads();
    const int len = cnt_s[0] + cnt_s[1] + cnt_s[2] + cnt_s[3];

    // ---- phase B: scores.  2 lanes per item; each dots 64 dims. ----
    const int item = t >> 1, half = t & 1;
    if (item < len) {
        float acc = 0.f, r[8];
        const size_t base = (size_t)it_s[item] * D + half * 64;
        const float4* hu4 = (const float4*)hu_s + half * 16;
        #pragma unroll
        for (int c = 0; c < 8; ++c) {
            load8f<BF>(Aw, base + 8 * c, r);
            float4 ha = hu4[2 * c], hb2 = hu4[2 * c + 1];
            acc += ha.x * r[0] + ha.y * r[1] + ha.z * r[2] + ha.w * r[3]
                 + hb2.x * r[4] + hb2.y * r[5] + hb2.z * r[6] + hb2.w * r[7];
        }
        acc += __shfl_xor(acc, 1);
        if (half == 0) sc_s[item] = acc;
    }
    // pad item list so phase D can run a branch-free multiple-of-32 loop;
    // pad rows alias it_s[0] (cache-hot after first touch).
    if (t >= len && t < 128) it_s[t] = it_s[0];
    __syncthreads();

    // ---- softmax over [0, len): shuffle reductions ----
    const float s = (t < len) ? sc_s[t] : -INFINITY;
    float mx = s;
    #pragma unroll
    for (int o = 32; o; o >>= 1) mx = fmaxf(mx, __shfl_xor(mx, o));
    if (ln == 0) redm_s[wv] = mx;
    __syncthreads();
    mx = fmaxf(fmaxf(redm_s[0], redm_s[1]), fmaxf(redm_s[2], redm_s[3]));
    const float e = (t < len) ? __expf(s - mx) : 0.f;
    float sm = e;
    #pragma unroll
    for (int o = 32; o; o >>= 1) sm += __shfl_xor(sm, o);
    if (ln == 0) reds_s[wv] = sm;
    __syncthreads();
    sm = reds_s[0] + reds_s[1] + reds_s[2] + reds_s[3];
    const float inv = (sm > 0.f) ? 1.f / sm : 0.f;
    if (t < 128) w_s[t] = e * inv;     // e==0 for t>=len -> zero weights on pads
    __syncthreads();

    // ---- phase D: h_x.  16 lanes per item, 8 dims/lane, 32 items/trip. ----
    const int g = t >> 4, m16 = t & 15;
    const int nit = (len + 31) & ~31;  // <= 128
    float acc[8];
    #pragma unroll
    for (int k = 0; k < 8; ++k) acc[k] = 0.f;
    for (int i = 0; i < nit; i += 32) {
        const int l0 = i + g, l1 = i + 16 + g;
        const float w0 = w_s[l0], w1 = w_s[l1];
        float r0[8], r1[8];
        load8f<BF>(emb_i, (size_t)it_s[l0] * D + 8 * m16, r0);
        load8f<BF>(emb_i, (size_t)it_s[l1] * D + 8 * m16, r1);
        #pragma unroll
        for (int k = 0; k < 8; ++k) acc[k] += w0 * r0[k] + w1 * r1[k];
    }
    #pragma unroll
    for (int k = 0; k < 8; ++k) part_s[g][8 * m16 + k] = acc[k];
    __syncthreads();

    // ---- combine + concat write ----
    if (t < D) {
        float hx = 0.f;
        #pragma unroll
        for (int gg = 0; gg < 16; ++gg) hx += part_s[gg][t];
        const float hbv = ld1<BF>(emb_b, (size_t)xb * D + t);
        h_out[(size_t)b * D2 + t]     = f2bf(hu);
        h_out[(size_t)b * D2 + D + t] = f2bf(hbv + hx);
    }
}

__global__ __launch_bounds__(256) void attn_kernel(
    const int* x_u, const int* x_b, const int* items, const void* mask,
    const void* emb_u, const void* emb_i, const void* emb_b, const void* A,
    unsigned short* h_out, int L, const int* __restrict__ flags)
{
    if (flags[0]) attn_body<true >(x_u, x_b, items, mask, flags[1], emb_u, emb_i, emb_b, A, h_out, L);
    else          attn_body<false>(x_u, x_b, items, mask, flags[1], emb_u, emb_i, emb_b, A, h_out, L);
}

// ---------------------------------------------------------------------------
// Kernel 2/3: Y = leaky_relu(X @ W^T + bias).  X [B,256] bf16 (ws), W [256,256]
// in detected dtype.  MFMA 16x16x32_bf16, fragments straight from global.
// ---------------------------------------------------------------------------
template<bool BF>
__device__ __forceinline__ bf16x8 load_w8(const void* W, size_t off) {
    if constexpr (BF) {
        return *(const bf16x8*)((const unsigned short*)W + off);
    } else {
        const float* p = (const float*)W + off;
        float4 a = *(const float4*)p;
        float4 b = *(const float4*)(p + 4);
        bf16x8 r;
        r[0] = (short)f2bf(a.x); r[1] = (short)f2bf(a.y);
        r[2] = (short)f2bf(a.z); r[3] = (short)f2bf(a.w);
        r[4] = (short)f2bf(b.x); r[5] = (short)f2bf(b.y);
        r[6] = (short)f2bf(b.z); r[7] = (short)f2bf(b.w);
        return r;
    }
}

template<bool BF>
__device__ __forceinline__ void fc_body(
    const unsigned short* __restrict__ X, const void* __restrict__ W,
    const void* __restrict__ bias, unsigned short* __restrict__ Y)
{
    const int tid  = threadIdx.x;
    const int wave = tid >> 6;
    const int lane = tid & 63;
    const int l16  = lane & 15;
    const int quad = lane >> 4;
    const int mt   = blockIdx.x * 16;

    bf16x8 afrag[8];
    const size_t abase = (size_t)(mt + l16) * D2 + quad * 8;
    #pragma unroll
    for (int kc = 0; kc < 8; ++kc)
        afrag[kc] = *(const bf16x8*)(X + abase + kc * 32);

    #pragma unroll
    for (int jj = 0; jj < 4; ++jj) {
        const int jt = wave * 4 + jj;
        const size_t bbase = (size_t)(jt * 16 + l16) * D2 + quad * 8;
        f32x4 acc = {0.f, 0.f, 0.f, 0.f};
        #pragma unroll
        for (int kc = 0; kc < 8; ++kc) {
            bf16x8 bfrag = load_w8<BF>(W, bbase + kc * 32);
            acc = __builtin_amdgcn_mfma_f32_16x16x32_bf16(afrag[kc], bfrag, acc, 0, 0, 0);
        }
        const int j  = jt * 16 + l16;
        const float bj = ld1<BF>(bias, j);
        #pragma unroll
        for (int r = 0; r < 4; ++r) {
            float v = acc[r] + bj;
            v = v > 0.f ? v : 0.01f * v;   // leaky_relu
            Y[(size_t)(mt + quad * 4 + r) * D2 + j] = f2bf(v);
        }
    }
}

__global__ __launch_bounds__(256) void fc_mfma_kernel(
    const unsigned short* X, const void* W, const void* bias,
    unsigned short* Y, const int* __restrict__ flags)
{
    if (flags[0]) fc_body<true >(X, W, bias, Y);
    else          fc_body<false>(X, W, bias, Y);
}

// ---------------------------------------------------------------------------
// Kernel 4: out[row] = dot(h2[row], out_w) + out_b.  One wave per row.
// ---------------------------------------------------------------------------
template<bool BF>
__device__ __forceinline__ void out_body(
    const unsigned short* __restrict__ X, const void* __restrict__ out_w,
    const void* __restrict__ out_b, void* __restrict__ out, int B)
{
    const int gid  = blockIdx.x * blockDim.x + threadIdx.x;
    const int row  = gid >> 6;
    const int lane = threadIdx.x & 63;
    if (row >= B) return;

    const uint2 xv = ((const uint2*)(X + (size_t)row * D2))[lane];  // 4 bf16
    const float x0 = bflo(xv.x), x1 = bfhi(xv.x), x2 = bflo(xv.y), x3 = bfhi(xv.y);
    float w0, w1, w2, w3;
    if constexpr (BF) {
        uint2 wv = ((const uint2*)out_w)[lane];
        w0 = bflo(wv.x); w1 = bfhi(wv.x); w2 = bflo(wv.y); w3 = bfhi(wv.y);
    } else {
        float4 wv = ((const float4*)out_w)[lane];
        w0 = wv.x; w1 = wv.y; w2 = wv.z; w3 = wv.w;
    }
    float acc = x0 * w0 + x1 * w1 + x2 * w2 + x3 * w3;
    #pragma unroll
    for (int off = 32; off; off >>= 1) acc += __shfl_down(acc, off);
    if (lane == 0) {
        const float v = acc + ld1<BF>(out_b, 0);
        if constexpr (BF) ((unsigned short*)out)[row] = f2bf(v);
        else              ((float*)out)[row] = v;
    }
}

__global__ __launch_bounds__(256) void out_kernel(
    const unsigned short* X, const void* out_w, const void* out_b,
    void* out, int B, const int* __restrict__ flags)
{
    if (flags[0]) out_body<true >(X, out_w, out_b, out, B);
    else          out_body<false>(X, out_w, out_b, out, B);
}

extern "C" void kernel_launch(void* const* d_in, const int* in_sizes, int n_in,
                              void* d_out, int out_size, void* d_ws, size_t ws_size,
                              hipStream_t stream) {
    const int*  x_u   = (const int*)d_in[0];
    const int*  x_b   = (const int*)d_in[1];
    const int*  items = (const int*)d_in[2];
    const void* mask  = d_in[3];
    const void* emb_u = d_in[4];
    const void* emb_i = d_in[5];
    const void* emb_b = d_in[6];
    const void* A     = d_in[7];
    const void* fc1_w = d_in[8];
    const void* fc1_b = d_in[9];
    const void* fc2_w = d_in[10];
    const void* fc2_b = d_in[11];
    const void* out_w = d_in[12];
    const void* out_b = d_in[13];

    const int B = in_sizes[0];
    const int L = in_sizes[2] / B;

    // ws layout: h [B,256] bf16 (4MB) | h1 [B,256] bf16 (4MB) | flags (64B)
    unsigned short* h  = (unsigned short*)d_ws;
    unsigned short* h1 = h + (size_t)B * D2;
    int* flags = (int*)(h1 + (size_t)B * D2);

    detect_kernel<<<1, 64, 0, stream>>>((const unsigned int*)emb_u,
                                        (const unsigned char*)mask, flags);
    attn_kernel<<<B, 256, 0, stream>>>(x_u, x_b, items, mask,
                                       emb_u, emb_i, emb_b, A, h, L, flags);
    fc_mfma_kernel<<<B / 16, 256, 0, stream>>>(h,  fc1_w, fc1_b, h1, flags);
    fc_mfma_kernel<<<B / 16, 256, 0, stream>>>(h1, fc2_w, fc2_b, h,  flags);
    out_kernel<<<B / 4, 256, 0, stream>>>(h, out_w, out_b, d_out, B, flags);
}